// Round 2
// baseline (906.027 us; speedup 1.0000x reference)
//
#include <hip/hip_runtime.h>

// VectorQuantizer on MI355X (gfx950)
// inputs:  d_in[0] = inputs  [32,64,64,64] f32 (NCHW)
//          d_in[1] = embedding [512,64] f32
//          d_in[2] = weight [512] f32
// output (all f32, concatenated):
//          [0 .. 2097151]   quantized NCHW
//          [2097152]        commitment_loss
//          [2097153]        perplexity
//          [2097154]        usage
//          [2097155 .. ]    indices (131072, written as float)

namespace {
constexpr int kB = 32, kC = 64, kH = 64, kW = 64;
constexpr int kK = 512, kD = 64;
constexpr int kHW = kH * kW;                 // 4096
constexpr int kCHW = kC * kHW;               // 262144
constexpr int kN = kB * kH * kW;             // 131072
constexpr int kQElems = kB * kC * kH * kW;   // 2097152
constexpr int kAssignBlocks = kN / 256;      // 512
constexpr float kGapThresh = 0.05f;          // f32 error << this << typical top-2 gap
}

// ---- kernel 0: embedding norms + zero histogram/flag counter ----------------
__global__ __launch_bounds__(512) void vq_prep(const float* __restrict__ emb,
                                               float* __restrict__ enorm,
                                               unsigned int* __restrict__ counts,
                                               unsigned int* __restrict__ flag_count) {
  const int k = threadIdx.x;  // 512 threads, one per codebook entry
  const float* __restrict__ ep = emb + k * kD;
  float s = 0.f;
#pragma unroll
  for (int d = 0; d < kD; ++d) s = fmaf(ep[d], ep[d], s);
  enorm[k] = s;
  counts[k] = 0u;
  if (k == 0) *flag_count = 0u;
}

// ---- kernel 1: f32 argmin + top-2 gap flagging + histogram + loss partials --
__global__ __launch_bounds__(256) void vq_assign(const float* __restrict__ in,
                                                 const float* __restrict__ emb,
                                                 const float* __restrict__ enorm,
                                                 float* __restrict__ idx_out,
                                                 unsigned int* __restrict__ counts,
                                                 float* __restrict__ partial,
                                                 unsigned int* __restrict__ flag_count,
                                                 unsigned int* __restrict__ flags,
                                                 unsigned int flag_cap) {
  const int n = blockIdx.x * 256 + threadIdx.x;
  const int b = n >> 12;        // n / (H*W)
  const int hw = n & 4095;      // n % (H*W)
  const float* __restrict__ xp = in + (size_t)b * kCHW + hw;

  float xr[kD];
#pragma unroll
  for (int d = 0; d < kD; ++d) xr[d] = xp[(size_t)d * kHW];  // coalesced per d

  float xnorm = 0.f;
#pragma unroll
  for (int d = 0; d < kD; ++d) xnorm = fmaf(xr[d], xr[d], xnorm);

  float best = 3.4e38f, second = 3.4e38f;
  int bidx = 0;
  for (int k = 0; k < kK; ++k) {
    const float* __restrict__ ep = emb + k * kD;  // wave-uniform -> s_load
    float a0 = 0.f, a1 = 0.f, a2 = 0.f, a3 = 0.f;
#pragma unroll
    for (int d = 0; d < kD; d += 4) {
      a0 = fmaf(xr[d + 0], ep[d + 0], a0);
      a1 = fmaf(xr[d + 1], ep[d + 1], a1);
      a2 = fmaf(xr[d + 2], ep[d + 2], a2);
      a3 = fmaf(xr[d + 3], ep[d + 3], a3);
    }
    const float dot = (a0 + a1) + (a2 + a3);
    const float s = fmaf(-2.f, dot, enorm[k]);  // d2 - xnorm (argmin-equivalent)
    if (s < best) { second = best; best = s; bidx = k; }  // strict < == first-min
    else if (s < second) { second = s; }
  }

  idx_out[n] = (float)bidx;
  atomicAdd(&counts[bidx], 1u);  // integer atomics: deterministic

  // ambiguous argmin -> flag for f64 refinement
  if (second - best < kGapThresh) {
    unsigned int slot = atomicAdd(flag_count, 1u);
    if (slot < flag_cap) flags[slot] = (unsigned int)n;
  }

  // per-point ||x - e||^2 = xnorm + (enorm - 2 dot); block-reduce -> partial
  float err = xnorm + best;
  __shared__ float red[256];
  red[threadIdx.x] = err;
  __syncthreads();
#pragma unroll
  for (int off = 128; off > 0; off >>= 1) {
    if (threadIdx.x < off) red[threadIdx.x] += red[threadIdx.x + off];
    __syncthreads();
  }
  if (threadIdx.x == 0) partial[blockIdx.x] = red[0];
}

// ---- kernel 1b: exact f64 re-argmin for flagged (near-tie) points -----------
__global__ __launch_bounds__(256) void vq_refine(const float* __restrict__ in,
                                                 const float* __restrict__ emb,
                                                 const unsigned int* __restrict__ flag_count,
                                                 const unsigned int* __restrict__ flags,
                                                 unsigned int flag_cap,
                                                 float* __restrict__ idx_out) {
  unsigned int cnt = *flag_count;
  if (cnt > flag_cap) cnt = flag_cap;
  const unsigned int stride = gridDim.x * blockDim.x;
  for (unsigned int i = blockIdx.x * blockDim.x + threadIdx.x; i < cnt; i += stride) {
    const int n = (int)flags[i];
    const int b = n >> 12;
    const int hw = n & 4095;
    const float* __restrict__ xp = in + (size_t)b * kCHW + hw;
    float xr[kD];
#pragma unroll
    for (int d = 0; d < kD; ++d) xr[d] = xp[(size_t)d * kHW];
    double best = 1e300;
    int bidx = 0;
    for (int k = 0; k < kK; ++k) {
      const float* __restrict__ ep = emb + k * kD;
      double s = 0.0;
#pragma unroll
      for (int d = 0; d < kD; ++d) {
        const double diff = (double)xr[d] - (double)ep[d];
        s = fma(diff, diff, s);
      }
      if (s < best) { best = s; bidx = k; }  // strict < == first-min
    }
    idx_out[n] = (float)bidx;
  }
}

// ---- kernel 2: scalars (loss, perplexity, usage) ----------------------------
__global__ __launch_bounds__(512) void vq_finalize(const float* __restrict__ weight,
                                                   const unsigned int* __restrict__ counts,
                                                   const float* __restrict__ partial,
                                                   float* __restrict__ out_scalars) {
  __shared__ float red[512];
  const int t = threadIdx.x;

  // perplexity = exp(-sum(avg * log(avg + 1e-10)))
  const float avg = (float)counts[t] / (float)kN;
  red[t] = avg * logf(avg + 1e-10f);
  __syncthreads();
#pragma unroll
  for (int off = 256; off > 0; off >>= 1) {
    if (t < off) red[t] += red[t + off];
    __syncthreads();
  }
  const float perp = expf(-red[0]);
  __syncthreads();

  // commitment loss = sum(partials) / (N*D), fixed-order tree -> deterministic
  red[t] = partial[t];
  __syncthreads();
#pragma unroll
  for (int off = 256; off > 0; off >>= 1) {
    if (t < off) red[t] += red[t + off];
    __syncthreads();
  }
  const float loss = red[0] / (float)((long long)kN * (long long)kD);
  __syncthreads();

  // usage = sum(weight >= 0.01)
  red[t] = (weight[t] >= 0.01f) ? 1.f : 0.f;
  __syncthreads();
#pragma unroll
  for (int off = 256; off > 0; off >>= 1) {
    if (t < off) red[t] += red[t + off];
    __syncthreads();
  }
  if (t == 0) {
    out_scalars[0] = loss;
    out_scalars[1] = perp;
    out_scalars[2] = red[0];
  }
}

// ---- kernel 3: quantized output, NHWC gather -> NCHW store ------------------
__global__ __launch_bounds__(256) void vq_gather(const float* __restrict__ emb,
                                                 const float* __restrict__ idx_f,
                                                 float* __restrict__ outq) {
  const int t = blockIdx.x * 256 + threadIdx.x;  // < 2097152, NCHW linear
  const int w = t & 63;
  const int h = (t >> 6) & 63;
  const int c = (t >> 12) & 63;
  const int b = t >> 18;
  const int n = (b << 12) | (h << 6) | w;        // point id
  const int idx = (int)idx_f[n];
  outq[t] = emb[idx * kD + c];                   // L2-resident gather
}

extern "C" void kernel_launch(void* const* d_in, const int* in_sizes, int n_in,
                              void* d_out, int out_size, void* d_ws, size_t ws_size,
                              hipStream_t stream) {
  const float* in = (const float*)d_in[0];
  const float* emb = (const float*)d_in[1];
  const float* weight = (const float*)d_in[2];
  float* out = (float*)d_out;

  // workspace layout (all 4-byte elems)
  float* ws_f = (float*)d_ws;
  unsigned int* ws_u = (unsigned int*)d_ws;
  float* enorm = ws_f;                    // [512]
  unsigned int* counts = ws_u + 512;      // [512]
  float* partial = ws_f + 1024;           // [512]
  unsigned int* flag_count = ws_u + 1536; // [1]
  unsigned int* flags = ws_u + 1537;      // [flag_cap]
  const size_t ws_elems = ws_size / 4;
  const unsigned int flag_cap =
      (ws_elems > 1537) ? (unsigned int)((ws_elems - 1537 < (size_t)kN) ? ws_elems - 1537 : (size_t)kN)
                        : 0u;

  float* outq = out;                   // [2097152]
  float* out_scalars = out + kQElems;  // [3]
  float* idx_out = out + kQElems + 3;  // [131072]

  vq_prep<<<1, 512, 0, stream>>>(emb, enorm, counts, flag_count);
  vq_assign<<<kAssignBlocks, 256, 0, stream>>>(in, emb, enorm, idx_out, counts, partial,
                                               flag_count, flags, flag_cap);
  vq_refine<<<64, 256, 0, stream>>>(in, emb, flag_count, flags, flag_cap, idx_out);
  vq_finalize<<<1, 512, 0, stream>>>(weight, counts, partial, out_scalars);
  vq_gather<<<kQElems / 256, 256, 0, stream>>>(emb, idx_out, outq);
}

// Round 3
// 725.724 us; speedup vs baseline: 1.2484x; 1.2484x over previous
//
#include <hip/hip_runtime.h>

// VectorQuantizer on MI355X (gfx950)
// inputs:  d_in[0] = inputs  [32,64,64,64] f32 (NCHW)
//          d_in[1] = embedding [512,64] f32
//          d_in[2] = weight [512] f32
// output (all f32, concatenated):
//          [0 .. 2097151]   quantized NCHW
//          [2097152]        commitment_loss
//          [2097153]        perplexity
//          [2097154]        usage
//          [2097155 .. ]    indices (131072, written as float)

namespace {
constexpr int kB = 32, kC = 64, kH = 64, kW = 64;
constexpr int kK = 512, kD = 64;
constexpr int kHW = kH * kW;                 // 4096
constexpr int kCHW = kC * kHW;               // 262144
constexpr int kN = kB * kH * kW;             // 131072
constexpr int kQElems = kB * kC * kH * kW;   // 2097152
constexpr int kAssignBlocks = kN / 256;      // 512
constexpr float kGapThresh = 0.05f;          // f32 error << this << typical top-2 gap
}

// ---- kernel 0: embedding norms + zero histogram/flag counter ----------------
__global__ __launch_bounds__(512) void vq_prep(const float* __restrict__ emb,
                                               float* __restrict__ enorm,
                                               unsigned int* __restrict__ counts,
                                               unsigned int* __restrict__ flag_count) {
  const int k = threadIdx.x;  // 512 threads, one per codebook entry
  const float* __restrict__ ep = emb + k * kD;
  float s = 0.f;
#pragma unroll
  for (int d = 0; d < kD; ++d) s = fmaf(ep[d], ep[d], s);
  enorm[k] = s;
  counts[k] = 0u;
  if (k == 0) *flag_count = 0u;
}

// ---- kernel 1: f32 argmin + top-2 gap flagging + histogram + loss partials --
__global__ __launch_bounds__(256) void vq_assign(const float* __restrict__ in,
                                                 const float* __restrict__ emb,
                                                 const float* __restrict__ enorm,
                                                 float* __restrict__ idx_out,
                                                 unsigned int* __restrict__ counts,
                                                 float* __restrict__ partial,
                                                 unsigned int* __restrict__ flag_count,
                                                 unsigned int* __restrict__ flags,
                                                 unsigned int flag_cap) {
  const int n = blockIdx.x * 256 + threadIdx.x;
  const int b = n >> 12;        // n / (H*W)
  const int hw = n & 4095;      // n % (H*W)
  const float* __restrict__ xp = in + (size_t)b * kCHW + hw;

  float xr[kD];
#pragma unroll
  for (int d = 0; d < kD; ++d) xr[d] = xp[(size_t)d * kHW];  // coalesced per d

  float xnorm = 0.f;
#pragma unroll
  for (int d = 0; d < kD; ++d) xnorm = fmaf(xr[d], xr[d], xnorm);

  float best = 3.4e38f, second = 3.4e38f;
  int bidx = 0;
  for (int k = 0; k < kK; ++k) {
    const float* __restrict__ ep = emb + k * kD;  // wave-uniform -> s_load
    float a0 = 0.f, a1 = 0.f, a2 = 0.f, a3 = 0.f;
#pragma unroll
    for (int d = 0; d < kD; d += 4) {
      a0 = fmaf(xr[d + 0], ep[d + 0], a0);
      a1 = fmaf(xr[d + 1], ep[d + 1], a1);
      a2 = fmaf(xr[d + 2], ep[d + 2], a2);
      a3 = fmaf(xr[d + 3], ep[d + 3], a3);
    }
    const float dot = (a0 + a1) + (a2 + a3);
    const float s = fmaf(-2.f, dot, enorm[k]);  // d2 - xnorm (argmin-equivalent)
    if (s < best) { second = best; best = s; bidx = k; }  // strict < == first-min
    else if (s < second) { second = s; }
  }

  idx_out[n] = (float)bidx;
  atomicAdd(&counts[bidx], 1u);  // integer atomics: deterministic

  // ambiguous argmin -> flag for f64 refinement
  if (second - best < kGapThresh) {
    unsigned int slot = atomicAdd(flag_count, 1u);
    if (slot < flag_cap) flags[slot] = (unsigned int)n;
  }

  // per-point ||x - e||^2 = xnorm + (enorm - 2 dot); block-reduce -> partial
  float err = xnorm + best;
  __shared__ float red[256];
  red[threadIdx.x] = err;
  __syncthreads();
#pragma unroll
  for (int off = 128; off > 0; off >>= 1) {
    if (threadIdx.x < off) red[threadIdx.x] += red[threadIdx.x + off];
    __syncthreads();
  }
  if (threadIdx.x == 0) partial[blockIdx.x] = red[0];
}

// ---- kernel 1b: exact f64 re-argmin, ONE WAVE per flagged point -------------
// Point id is wave-uniform -> x[] arrives via scalar loads. Lane l scans
// k in [8l, 8l+8); 64-lane butterfly argmin with first-min tie-break.
__global__ __launch_bounds__(256) void vq_refine(const float* __restrict__ in,
                                                 const float* __restrict__ emb,
                                                 const unsigned int* __restrict__ flag_count,
                                                 const unsigned int* __restrict__ flags,
                                                 unsigned int flag_cap,
                                                 float* __restrict__ idx_out) {
  unsigned int cnt = *flag_count;
  if (cnt > flag_cap) cnt = flag_cap;
  const int lane = threadIdx.x & 63;
  const unsigned int wave_id = blockIdx.x * 4u + (threadIdx.x >> 6);
  const unsigned int wave_stride = gridDim.x * 4u;

  for (unsigned int i = wave_id; i < cnt; i += wave_stride) {
    const int n = (int)flags[i];          // wave-uniform
    const int b = n >> 12;
    const int hw = n & 4095;
    const float* __restrict__ xp = in + (size_t)b * kCHW + hw;

    float xr[kD];
#pragma unroll
    for (int d = 0; d < kD; ++d) xr[d] = xp[(size_t)d * kHW];  // uniform -> s_load

    double best = 1e300;
    int bidx = 0;
#pragma unroll
    for (int kk = 0; kk < 8; ++kk) {
      const int k = lane * 8 + kk;        // lane covers contiguous k-range
      const float* __restrict__ ep = emb + k * kD;
      double s0 = 0.0, s1 = 0.0;
#pragma unroll
      for (int d = 0; d < kD; d += 2) {
        const double df0 = (double)xr[d]     - (double)ep[d];
        const double df1 = (double)xr[d + 1] - (double)ep[d + 1];
        s0 = fma(df0, df0, s0);
        s1 = fma(df1, df1, s1);
      }
      const double s = s0 + s1;
      if (s < best) { best = s; bidx = k; }  // strict < == first-min in-lane
    }

    // cross-lane first-min: lexicographic (value, index)
#pragma unroll
    for (int off = 32; off > 0; off >>= 1) {
      const double ob = __shfl_xor(best, off, 64);
      const int oi = __shfl_xor(bidx, off, 64);
      if (ob < best || (ob == best && oi < bidx)) { best = ob; bidx = oi; }
    }
    if (lane == 0) idx_out[n] = (float)bidx;
  }
}

// ---- kernel 2: scalars (loss, perplexity, usage) ----------------------------
__global__ __launch_bounds__(512) void vq_finalize(const float* __restrict__ weight,
                                                   const unsigned int* __restrict__ counts,
                                                   const float* __restrict__ partial,
                                                   float* __restrict__ out_scalars) {
  __shared__ float red[512];
  const int t = threadIdx.x;

  // perplexity = exp(-sum(avg * log(avg + 1e-10)))
  const float avg = (float)counts[t] / (float)kN;
  red[t] = avg * logf(avg + 1e-10f);
  __syncthreads();
#pragma unroll
  for (int off = 256; off > 0; off >>= 1) {
    if (t < off) red[t] += red[t + off];
    __syncthreads();
  }
  const float perp = expf(-red[0]);
  __syncthreads();

  // commitment loss = sum(partials) / (N*D), fixed-order tree -> deterministic
  red[t] = partial[t];
  __syncthreads();
#pragma unroll
  for (int off = 256; off > 0; off >>= 1) {
    if (t < off) red[t] += red[t + off];
    __syncthreads();
  }
  const float loss = red[0] / (float)((long long)kN * (long long)kD);
  __syncthreads();

  // usage = sum(weight >= 0.01)
  red[t] = (weight[t] >= 0.01f) ? 1.f : 0.f;
  __syncthreads();
#pragma unroll
  for (int off = 256; off > 0; off >>= 1) {
    if (t < off) red[t] += red[t + off];
    __syncthreads();
  }
  if (t == 0) {
    out_scalars[0] = loss;
    out_scalars[1] = perp;
    out_scalars[2] = red[0];
  }
}

// ---- kernel 3: quantized output, NHWC gather -> NCHW store ------------------
__global__ __launch_bounds__(256) void vq_gather(const float* __restrict__ emb,
                                                 const float* __restrict__ idx_f,
                                                 float* __restrict__ outq) {
  const int t = blockIdx.x * 256 + threadIdx.x;  // < 2097152, NCHW linear
  const int w = t & 63;
  const int h = (t >> 6) & 63;
  const int c = (t >> 12) & 63;
  const int b = t >> 18;
  const int n = (b << 12) | (h << 6) | w;        // point id
  const int idx = (int)idx_f[n];
  outq[t] = emb[idx * kD + c];                   // L2-resident gather
}

extern "C" void kernel_launch(void* const* d_in, const int* in_sizes, int n_in,
                              void* d_out, int out_size, void* d_ws, size_t ws_size,
                              hipStream_t stream) {
  const float* in = (const float*)d_in[0];
  const float* emb = (const float*)d_in[1];
  const float* weight = (const float*)d_in[2];
  float* out = (float*)d_out;

  // workspace layout (all 4-byte elems)
  float* ws_f = (float*)d_ws;
  unsigned int* ws_u = (unsigned int*)d_ws;
  float* enorm = ws_f;                    // [512]
  unsigned int* counts = ws_u + 512;      // [512]
  float* partial = ws_f + 1024;           // [512]
  unsigned int* flag_count = ws_u + 1536; // [1]
  unsigned int* flags = ws_u + 1537;      // [flag_cap]
  const size_t ws_elems = ws_size / 4;
  const unsigned int flag_cap =
      (ws_elems > 1537) ? (unsigned int)((ws_elems - 1537 < (size_t)kN) ? ws_elems - 1537 : (size_t)kN)
                        : 0u;

  float* outq = out;                   // [2097152]
  float* out_scalars = out + kQElems;  // [3]
  float* idx_out = out + kQElems + 3;  // [131072]

  vq_prep<<<1, 512, 0, stream>>>(emb, enorm, counts, flag_count);
  vq_assign<<<kAssignBlocks, 256, 0, stream>>>(in, emb, enorm, idx_out, counts, partial,
                                               flag_count, flags, flag_cap);
  vq_refine<<<256, 256, 0, stream>>>(in, emb, flag_count, flags, flag_cap, idx_out);
  vq_finalize<<<1, 512, 0, stream>>>(weight, counts, partial, out_scalars);
  vq_gather<<<kQElems / 256, 256, 0, stream>>>(emb, idx_out, outq);
}

// Round 4
// 343.104 us; speedup vs baseline: 2.6407x; 2.1152x over previous
//
#include <hip/hip_runtime.h>

// VectorQuantizer on MI355X (gfx950)
// inputs:  d_in[0] = inputs  [32,64,64,64] f32 (NCHW)
//          d_in[1] = embedding [512,64] f32
//          d_in[2] = weight [512] f32
// output (all f32, concatenated):
//          [0 .. 2097151]   quantized NCHW
//          [2097152]        commitment_loss
//          [2097153]        perplexity
//          [2097154]        usage
//          [2097155 .. ]    indices (131072, written as float)

namespace {
constexpr int kB = 32, kC = 64, kH = 64, kW = 64;
constexpr int kK = 512, kD = 64;
constexpr int kHW = kH * kW;                 // 4096
constexpr int kCHW = kC * kHW;               // 262144
constexpr int kN = kB * kH * kW;             // 131072
constexpr int kQElems = kB * kC * kH * kW;   // 2097152
constexpr int kAssignBlocks = kN / 64;       // 2048 (64 points/block, 4 k-quarters)
constexpr float kGapThresh = 0.02f;          // f32 s-error <= ~3e-4 -> 60x margin
}

// ---- kernel 0: embedding norms + zero histogram/flag counter ----------------
__global__ __launch_bounds__(512) void vq_prep(const float* __restrict__ emb,
                                               float* __restrict__ enorm,
                                               unsigned int* __restrict__ counts,
                                               unsigned int* __restrict__ flag_count) {
  const int k = threadIdx.x;  // 512 threads, one per codebook entry
  const float* __restrict__ ep = emb + k * kD;
  float s = 0.f;
#pragma unroll
  for (int d = 0; d < kD; ++d) s = fmaf(ep[d], ep[d], s);
  enorm[k] = s;
  counts[k] = 0u;
  if (k == 0) *flag_count = 0u;
}

// ---- kernel 1: f32 argmin, K split across the block's 4 waves ---------------
// Block = 256 threads = 64 points x 4 k-quarters. Wave w (uniform) scans
// k in [128w, 128w+128) for all 64 points; per-wave (best,second,idx) triples
// merge through LDS with lowest-k tie-break (== jnp.argmin first-min).
// Embedding row pointer stays wave-uniform (readfirstlane) -> s_load + SGPR
// operand to v_fmac; 2048 blocks give ~16 waves/CU for latency hiding.
__global__ __launch_bounds__(256, 4) void vq_assign(const float* __restrict__ in,
                                                    const float* __restrict__ emb,
                                                    const float* __restrict__ enorm,
                                                    float* __restrict__ idx_out,
                                                    unsigned int* __restrict__ counts,
                                                    float* __restrict__ partial,
                                                    unsigned int* __restrict__ flag_count,
                                                    unsigned int* __restrict__ flags,
                                                    unsigned int flag_cap) {
  const int lane = threadIdx.x & 63;
  // Force wave-uniformity into an SGPR so emb row loads stay scalar.
  const int kq = __builtin_amdgcn_readfirstlane(threadIdx.x >> 6);
  const int k0 = kq * (kK / 4);

  const int n = blockIdx.x * 64 + lane;
  const int b = n >> 12;        // n / (H*W)
  const int hw = n & 4095;      // n % (H*W)
  const float* __restrict__ xp = in + (size_t)b * kCHW + hw;

  float xr[kD];
#pragma unroll
  for (int d = 0; d < kD; ++d) xr[d] = xp[(size_t)d * kHW];  // coalesced per d

  float xnorm = 0.f;
#pragma unroll
  for (int d = 0; d < kD; ++d) xnorm = fmaf(xr[d], xr[d], xnorm);

  float best = 3.4e38f, second = 3.4e38f;
  int bidx = k0;
  for (int j = 0; j < kK / 4; ++j) {
    const int k = k0 + j;                         // uniform (SGPR + uniform loop)
    const float* __restrict__ ep = emb + k * kD;  // -> s_load_dwordx16 x4
    float a0 = 0.f, a1 = 0.f, a2 = 0.f, a3 = 0.f;
#pragma unroll
    for (int d = 0; d < kD; d += 4) {
      a0 = fmaf(xr[d + 0], ep[d + 0], a0);
      a1 = fmaf(xr[d + 1], ep[d + 1], a1);
      a2 = fmaf(xr[d + 2], ep[d + 2], a2);
      a3 = fmaf(xr[d + 3], ep[d + 3], a3);
    }
    const float dot = (a0 + a1) + (a2 + a3);
    const float s = fmaf(-2.f, dot, enorm[k]);  // d2 - xnorm (argmin-equivalent)
    if (s < best) { second = best; best = s; bidx = k; }  // strict < == first-min
    else if (s < second) { second = s; }
  }

  // merge the 4 k-quarter triples per point through LDS
  __shared__ float lb[4][64];
  __shared__ float ls[4][64];
  __shared__ int   li[4][64];
  lb[kq][lane] = best;
  ls[kq][lane] = second;
  li[kq][lane] = bidx;
  __syncthreads();

  if (threadIdx.x < 64) {
    const int l = threadIdx.x;
    float gb = lb[0][l], gs = ls[0][l];
    int gi = li[0][l];
#pragma unroll
    for (int w = 1; w < 4; ++w) {
      const float bw = lb[w][l], sw = ls[w][l];
      const int iw = li[w][l];
      if (bw < gb) { gs = fminf(gb, sw); gb = bw; gi = iw; }  // lower w = lower k wins ties
      else         { gs = fminf(gs, bw); }
    }

    idx_out[blockIdx.x * 64 + l] = (float)gi;
    atomicAdd(&counts[gi], 1u);  // integer atomics: deterministic

    if (gs - gb < kGapThresh) {  // ambiguous argmin -> f64 refinement
      unsigned int slot = atomicAdd(flag_count, 1u);
      if (slot < flag_cap) flags[slot] = (unsigned int)(blockIdx.x * 64 + l);
    }

    // per-point ||x - e||^2 = xnorm + (enorm - 2 dot); wave-reduce -> partial
    float v = xnorm + gb;
#pragma unroll
    for (int off = 32; off > 0; off >>= 1) v += __shfl_down(v, off, 64);
    if (l == 0) partial[blockIdx.x] = v;
  }
}

// ---- kernel 1b: exact f64 re-argmin, ONE WAVE per flagged point -------------
__global__ __launch_bounds__(256) void vq_refine(const float* __restrict__ in,
                                                 const float* __restrict__ emb,
                                                 const unsigned int* __restrict__ flag_count,
                                                 const unsigned int* __restrict__ flags,
                                                 unsigned int flag_cap,
                                                 float* __restrict__ idx_out) {
  unsigned int cnt = *flag_count;
  if (cnt > flag_cap) cnt = flag_cap;
  const int lane = threadIdx.x & 63;
  const unsigned int wave_id = blockIdx.x * 4u + (threadIdx.x >> 6);
  const unsigned int wave_stride = gridDim.x * 4u;

  for (unsigned int i = wave_id; i < cnt; i += wave_stride) {
    const int n = (int)flags[i];          // wave-uniform
    const int b = n >> 12;
    const int hw = n & 4095;
    const float* __restrict__ xp = in + (size_t)b * kCHW + hw;

    float xr[kD];
#pragma unroll
    for (int d = 0; d < kD; ++d) xr[d] = xp[(size_t)d * kHW];  // uniform -> s_load

    double best = 1e300;
    int bidx = 0;
#pragma unroll
    for (int kk = 0; kk < 8; ++kk) {
      const int k = lane * 8 + kk;        // lane covers contiguous k-range
      const float* __restrict__ ep = emb + k * kD;
      double s0 = 0.0, s1 = 0.0;
#pragma unroll
      for (int d = 0; d < kD; d += 2) {
        const double df0 = (double)xr[d]     - (double)ep[d];
        const double df1 = (double)xr[d + 1] - (double)ep[d + 1];
        s0 = fma(df0, df0, s0);
        s1 = fma(df1, df1, s1);
      }
      const double s = s0 + s1;
      if (s < best) { best = s; bidx = k; }  // strict < == first-min in-lane
    }

    // cross-lane first-min: lexicographic (value, index)
#pragma unroll
    for (int off = 32; off > 0; off >>= 1) {
      const double ob = __shfl_xor(best, off, 64);
      const int oi = __shfl_xor(bidx, off, 64);
      if (ob < best || (ob == best && oi < bidx)) { best = ob; bidx = oi; }
    }
    if (lane == 0) idx_out[n] = (float)bidx;
  }
}

// ---- kernel 2: scalars (loss, perplexity, usage) ----------------------------
__global__ __launch_bounds__(512) void vq_finalize(const float* __restrict__ weight,
                                                   const unsigned int* __restrict__ counts,
                                                   const float* __restrict__ partial,
                                                   float* __restrict__ out_scalars) {
  __shared__ float red[512];
  const int t = threadIdx.x;

  // perplexity = exp(-sum(avg * log(avg + 1e-10)))
  const float avg = (float)counts[t] / (float)kN;
  red[t] = avg * logf(avg + 1e-10f);
  __syncthreads();
#pragma unroll
  for (int off = 256; off > 0; off >>= 1) {
    if (t < off) red[t] += red[t + off];
    __syncthreads();
  }
  const float perp = expf(-red[0]);
  __syncthreads();

  // commitment loss = sum of 2048 partials, fixed-order -> deterministic
  red[t] = (partial[t] + partial[t + 512]) + (partial[t + 1024] + partial[t + 1536]);
  __syncthreads();
#pragma unroll
  for (int off = 256; off > 0; off >>= 1) {
    if (t < off) red[t] += red[t + off];
    __syncthreads();
  }
  const float loss = red[0] / (float)((long long)kN * (long long)kD);
  __syncthreads();

  // usage = sum(weight >= 0.01)
  red[t] = (weight[t] >= 0.01f) ? 1.f : 0.f;
  __syncthreads();
#pragma unroll
  for (int off = 256; off > 0; off >>= 1) {
    if (t < off) red[t] += red[t + off];
    __syncthreads();
  }
  if (t == 0) {
    out_scalars[0] = loss;
    out_scalars[1] = perp;
    out_scalars[2] = red[0];
  }
}

// ---- kernel 3: quantized output, NHWC gather -> NCHW store ------------------
__global__ __launch_bounds__(256) void vq_gather(const float* __restrict__ emb,
                                                 const float* __restrict__ idx_f,
                                                 float* __restrict__ outq) {
  const int t = blockIdx.x * 256 + threadIdx.x;  // < 2097152, NCHW linear
  const int w = t & 63;
  const int h = (t >> 6) & 63;
  const int c = (t >> 12) & 63;
  const int b = t >> 18;
  const int n = (b << 12) | (h << 6) | w;        // point id
  const int idx = (int)idx_f[n];
  outq[t] = emb[idx * kD + c];                   // L2-resident gather
}

extern "C" void kernel_launch(void* const* d_in, const int* in_sizes, int n_in,
                              void* d_out, int out_size, void* d_ws, size_t ws_size,
                              hipStream_t stream) {
  const float* in = (const float*)d_in[0];
  const float* emb = (const float*)d_in[1];
  const float* weight = (const float*)d_in[2];
  float* out = (float*)d_out;

  // workspace layout (all 4-byte elems)
  float* ws_f = (float*)d_ws;
  unsigned int* ws_u = (unsigned int*)d_ws;
  float* enorm = ws_f;                    // [512]
  unsigned int* counts = ws_u + 512;      // [512]
  float* partial = ws_f + 1024;           // [2048]
  unsigned int* flag_count = ws_u + 3072; // [1]
  unsigned int* flags = ws_u + 3073;      // [flag_cap]
  const size_t ws_elems = ws_size / 4;
  const unsigned int flag_cap =
      (ws_elems > 3073) ? (unsigned int)((ws_elems - 3073 < (size_t)kN) ? ws_elems - 3073 : (size_t)kN)
                        : 0u;

  float* outq = out;                   // [2097152]
  float* out_scalars = out + kQElems;  // [3]
  float* idx_out = out + kQElems + 3;  // [131072]

  vq_prep<<<1, 512, 0, stream>>>(emb, enorm, counts, flag_count);
  vq_assign<<<kAssignBlocks, 256, 0, stream>>>(in, emb, enorm, idx_out, counts, partial,
                                               flag_count, flags, flag_cap);
  vq_refine<<<512, 256, 0, stream>>>(in, emb, flag_count, flags, flag_cap, idx_out);
  vq_finalize<<<1, 512, 0, stream>>>(weight, counts, partial, out_scalars);
  vq_gather<<<kQElems / 256, 256, 0, stream>>>(emb, idx_out, outq);
}